// Round 13
// baseline (215.544 us; speedup 1.0000x reference)
//
#include <hip/hip_runtime.h>

// 192^3 structure tensor, fused z-streaming pipeline (4 dispatches):
//   S0: setup_coef    (extract 1D rank-1 factors from the provided 3D kernels)
//   S1: blur3d<6,1,false>   x -> xs
//   S2: grad3d<16>    xs -> G[3]      (gz,gy,gx only; products deferred to S3)
//   S3: blur3d<32,6,true>   G -> out  (products formed in regs at staging time)
// r8-proven schedule (stage -> bar -> xconv -> bar -> yconv/ring/store), r8-proven
// LDS classes. r13 work-compression: 8-output xconv tasks (14 rd / 8 out, stride-41
// bank-check: 9dr+8dg=0 mod 32 has no in-range solutions -> 0-conflict) and 2-row
// yconv micro-tile (8 b128 / 2 rows; stride-32 xt, each 8-lane phase = one row-pair
// covering all 32 banks -> conflict-free; r5's failure was stride-64, not 2-row).
// VGPR growth is free: S3 occupancy is grid-limited (5.06 blk/CU = 20 waves).

constexpr int D  = 192;
constexpr int DD = D * D;                  // 36864
constexpr long long V = (long long)D * DD; // 7077888

// coef layout (floats):
//  [0..6] ga  [7..13] gb  [14..20] gc   (gauss z,y,x)
//  [21..29] az (9)  [30..34] bz (5)  [35..39] cz (5)
//  [40..44] ay (5)  [45..53] by (9)  [54..58] cy (5, dup)
//  [59..63] ax (5)  [64..68] bx (5)  [69..77] cx (9)
__global__ void setup_coef(const float* __restrict__ g3, const float* __restrict__ kz,
                           const float* __restrict__ ky, const float* __restrict__ kx,
                           float* __restrict__ c) {
    if (blockIdx.x != 0 || threadIdx.x != 0) return;
    float Tg = g3[0];
    for (int i = 0; i < 7; ++i) c[0 + i]  = g3[i * 49];
    for (int j = 0; j < 7; ++j) c[7 + j]  = g3[j * 7] / Tg;
    for (int k = 0; k < 7; ++k) c[14 + k] = g3[k] / Tg;
    float Tz = kz[0];                      // kz: [9,5,5]
    for (int i = 0; i < 9; ++i) c[21 + i] = kz[i * 25];
    for (int j = 0; j < 5; ++j) c[30 + j] = kz[j * 5] / Tz;
    for (int k = 0; k < 5; ++k) c[35 + k] = kz[k] / Tz;
    float Ty = ky[0];                      // ky: [5,9,5]
    for (int i = 0; i < 5; ++i) c[40 + i] = ky[i * 45];
    for (int j = 0; j < 9; ++j) c[45 + j] = ky[j * 5] / Ty;
    for (int k = 0; k < 5; ++k) c[54 + k] = ky[k] / Ty;
    float Tx = kx[0];                      // kx: [5,5,9]
    for (int i = 0; i < 5; ++i) c[59 + i] = kx[i * 45];
    for (int j = 0; j < 5; ++j) c[64 + j] = kx[j * 9] / Tx;
    for (int k = 0; k < 9; ++k) c[69 + k] = kx[k] / Tx;
}

// Bounds-checked float4 load from one z-slice (row gy, cols gx..gx+3), zero-padded.
__device__ inline float4 ldg4(const float* __restrict__ slice, int gy, int gx) {
    float4 v = {0.f, 0.f, 0.f, 0.f};
    if ((unsigned)gy < (unsigned)D) {
        const float* row = slice + gy * D;
        if ((unsigned)gx <= (unsigned)(D - 4)) {
            v = *(const float4*)(row + gx);
        } else {
            float* pv = (float*)&v;
#pragma unroll
            for (int j = 0; j < 4; ++j) {
                const int g = gx + j;
                if ((unsigned)g < (unsigned)D) pv[j] = row[g];
            }
        }
    }
    return v;
}

// Dual-field bounds-hoisted load: computes bounds once, loads A and B rows.
__device__ inline void ldg4x2(const float* __restrict__ slA, const float* __restrict__ slB,
                              int gy, int gx, float4& a, float4& b) {
    a = make_float4(0.f, 0.f, 0.f, 0.f);
    b = a;
    if ((unsigned)gy < (unsigned)D) {
        const int ro = gy * D;
        if ((unsigned)gx <= (unsigned)(D - 4)) {
            a = *(const float4*)(slA + ro + gx);
            b = *(const float4*)(slB + ro + gx);
        } else {
            float* pa = (float*)&a;
            float* pb = (float*)&b;
#pragma unroll
            for (int j = 0; j < 4; ++j) {
                const int g = gx + j;
                if ((unsigned)g < (unsigned)D) { pa[j] = slA[ro + g]; pb[j] = slB[ro + g]; }
            }
        }
    }
}

// Staging task li -> (row li/10, quad li%10) of a (rows x 40) region, stride-41 LDS.
__device__ inline float4 ld_task10(const float* __restrict__ slice, int y0, int x0, int li) {
    const int r = li / 10, q = li % 10;
    return ldg4(slice, y0 + r, x0 + q * 4);
}
__device__ inline void st_task41(float* __restrict__ dst, int li, float4 v) {
    const int r = li / 10, q = li % 10;
    float* d = &dst[r * 41 + q * 4];
    d[0] = v.x; d[1] = v.y; d[2] = v.z; d[3] = v.w;   // b32 class: conflict-free
}

// ---- fused separable 3D blur, z-streaming, 32x32 tile, register z-ring ----
// PROD=true: stage task loads two gradient fields and multiplies (product on the fly).
// 1D grid, XCD-swizzled; work = tile + 36*(ch + NCH*seg)
template <int SEG, int NCH, bool PROD>
__global__ __launch_bounds__(256) void blur3d(const float* __restrict__ in,
                                              float* __restrict__ out,
                                              const float* __restrict__ coef) {
    __shared__ float raw[38 * 41];
    __shared__ float xt[38][32];
    const int cpx = gridDim.x >> 3;
    int w = (blockIdx.x & 7) * cpx + (blockIdx.x >> 3);
    const int tile = w % 36; w /= 36;
    const int ch = w % NCH;
    const int seg = w / NCH;
    const int tx0 = (tile % 6) * 32, ty0 = (tile / 6) * 32;
    const int z0 = seg * SEG;
    // product channel -> gradient-field pair: [Jzz,Jzy,Jzx,Jyy,Jyx,Jxx]
    const int IA[6] = {0, 1, 2, 1, 2, 2};
    const int IB[6] = {0, 0, 0, 1, 1, 2};
    const float* srcA = in + (long long)(PROD ? IA[ch] : ch) * V;
    const float* srcB = in + (long long)(PROD ? IB[ch] : ch) * V;
    const bool same = !PROD || (IA[ch] == IB[ch]);
    float* dst = out + (long long)ch * V;
    float ga[7], gb[7], gc[7];
#pragma unroll
    for (int k = 0; k < 7; ++k) { ga[k] = coef[k]; gb[k] = coef[7 + k]; gc[k] = coef[14 + k]; }
    const int tid = threadIdx.x;
    // xconv: 152 8-output tasks (38 rows x 4 octs)
    const int xr = tid >> 2, xg = tid & 3;
    // yconv: 128 2-row tasks (16 row-pairs x 8 quads)
    const int pr = tid >> 3;                 // 0..15 (tid<128)
    const int yc = (tid & 7) * 4;            // 0,4,..,28
    float4 ring0[7], ring1[7];
#pragma unroll
    for (int k = 0; k < 7; ++k) {
        ring0[k] = make_float4(0.f, 0.f, 0.f, 0.f);
        ring1[k] = make_float4(0.f, 0.f, 0.f, 0.f);
    }

    for (int s = z0 - 3; s < z0 + SEG + 3; ++s) {
        const bool inz = (s >= 0 && s < D);
        if (inz) {
            const float* slA = srcA + (long long)s * DD;
            const float* slB = srcB + (long long)s * DD;
            if (same) {
                for (int li = tid; li < 380; li += 256) {
                    float4 a = ld_task10(slA, ty0 - 3, tx0 - 4, li);
                    if (PROD) { a.x *= a.x; a.y *= a.y; a.z *= a.z; a.w *= a.w; }
                    st_task41(raw, li, a);
                }
            } else {
                for (int li = tid; li < 380; li += 256) {
                    const int r = li / 10, q = li % 10;
                    float4 a, b;
                    ldg4x2(slA, slB, ty0 - 3 + r, tx0 - 4 + q * 4, a, b);
                    a.x *= b.x; a.y *= b.y; a.z *= b.z; a.w *= b.w;
                    float* d = &raw[r * 41 + q * 4];
                    d[0] = a.x; d[1] = a.y; d[2] = a.z; d[3] = a.w;
                }
            }
        }
        __syncthreads();                       // raw ready; prior xt readers done
        if (inz && tid < 152) {
            // 8-output sliding-window xconv: 14 scalar reads -> 8 outputs, 2 b128 writes
            const float* rp = &raw[xr * 41 + 8 * xg + 1];
            float win[14];
#pragma unroll
            for (int i = 0; i < 14; ++i) win[i] = rp[i];
            float4 o0 = make_float4(0.f, 0.f, 0.f, 0.f);
            float4 o1 = make_float4(0.f, 0.f, 0.f, 0.f);
#pragma unroll
            for (int k = 0; k < 7; ++k) {
                o0.x += gc[k] * win[k];
                o0.y += gc[k] * win[k + 1];
                o0.z += gc[k] * win[k + 2];
                o0.w += gc[k] * win[k + 3];
                o1.x += gc[k] * win[k + 4];
                o1.y += gc[k] * win[k + 5];
                o1.z += gc[k] * win[k + 6];
                o1.w += gc[k] * win[k + 7];
            }
            *(float4*)&xt[xr][8 * xg] = o0;
            *(float4*)&xt[xr][8 * xg + 4] = o1;
        }
        __syncthreads();                       // xt ready; raw readers done
        if (tid < 128) {
            float4 yv0 = make_float4(0.f, 0.f, 0.f, 0.f);
            float4 yv1 = make_float4(0.f, 0.f, 0.f, 0.f);
            if (inz) {
                // 2-row yconv: 8 b128 reads serve rows 2pr and 2pr+1
                float4 X[8];
#pragma unroll
                for (int k = 0; k < 8; ++k) X[k] = *(const float4*)&xt[2 * pr + k][yc];
#pragma unroll
                for (int k = 0; k < 7; ++k) {
                    yv0.x += gb[k] * X[k].x; yv0.y += gb[k] * X[k].y;
                    yv0.z += gb[k] * X[k].z; yv0.w += gb[k] * X[k].w;
                    yv1.x += gb[k] * X[k + 1].x; yv1.y += gb[k] * X[k + 1].y;
                    yv1.z += gb[k] * X[k + 1].z; yv1.w += gb[k] * X[k + 1].w;
                }
            }
#pragma unroll
            for (int k = 0; k < 6; ++k) { ring0[k] = ring0[k + 1]; ring1[k] = ring1[k + 1]; }
            ring0[6] = yv0; ring1[6] = yv1;
            const int z = s - 3;
            if (z >= z0) {
                float4 a0 = make_float4(0.f, 0.f, 0.f, 0.f);
                float4 a1 = make_float4(0.f, 0.f, 0.f, 0.f);
#pragma unroll
                for (int k = 0; k < 7; ++k) {
                    a0.x += ga[k] * ring0[k].x; a0.y += ga[k] * ring0[k].y;
                    a0.z += ga[k] * ring0[k].z; a0.w += ga[k] * ring0[k].w;
                    a1.x += ga[k] * ring1[k].x; a1.y += ga[k] * ring1[k].y;
                    a1.z += ga[k] * ring1[k].z; a1.w += ga[k] * ring1[k].w;
                }
                float* o = dst + (long long)z * DD + (ty0 + 2 * pr) * D + tx0 + yc;
                *(float4*)o = a0;
                *(float4*)(o + D) = a1;
            }
        }
    }
}

// ---- fused gradients, z-streaming, 32x16 tile, register rings ----
// 1D grid, XCD-swizzled; work = tile + 72*seg; writes gz,gy,gx to G[0..2]
template <int SEG>
__global__ __launch_bounds__(256) void grad3d(const float* __restrict__ xs,
                                              float* __restrict__ G,
                                              const float* __restrict__ coef) {
    __shared__ float raw[24 * 41];
    __shared__ float X1[24][32];
    __shared__ float X2[24][32];
    const int cpx = gridDim.x >> 3;
    int w = (blockIdx.x & 7) * cpx + (blockIdx.x >> 3);
    const int tile = w % 72;
    const int seg = w / 72;
    const int tx0 = (tile % 6) * 32, ty0 = (tile / 6) * 16;
    const int z0 = seg * SEG;
    float az[9], ay[5], ax[5], bz[5], by[9], bx[5], czc[5], cxc[9];
#pragma unroll
    for (int k = 0; k < 9; ++k) az[k] = coef[21 + k];
#pragma unroll
    for (int k = 0; k < 5; ++k) ay[k] = coef[40 + k];
#pragma unroll
    for (int k = 0; k < 5; ++k) ax[k] = coef[59 + k];
#pragma unroll
    for (int k = 0; k < 5; ++k) bz[k] = coef[30 + k];
#pragma unroll
    for (int k = 0; k < 9; ++k) by[k] = coef[45 + k];
#pragma unroll
    for (int k = 0; k < 5; ++k) bx[k] = coef[64 + k];
#pragma unroll
    for (int k = 0; k < 5; ++k) czc[k] = coef[35 + k];
#pragma unroll
    for (int k = 0; k < 9; ++k) cxc[k] = coef[69 + k];
    const int tid = threadIdx.x;
    const int rr = tid >> 4;                   // 0..15
    const int cc = (tid & 15) * 2;             // 0,2,..,30
    // xconv: 96 8-output tasks (24 rows x 4 octs)
    const int xr = tid >> 2, xg = tid & 3;
    float2 R1[9], R2[7], R3[7];
#pragma unroll
    for (int k = 0; k < 9; ++k) R1[k] = make_float2(0.f, 0.f);
#pragma unroll
    for (int k = 0; k < 7; ++k) { R2[k] = make_float2(0.f, 0.f); R3[k] = make_float2(0.f, 0.f); }

    for (int s = z0 - 4; s < z0 + SEG + 4; ++s) {
        const bool inz = (s >= 0 && s < D);
        if (inz) {
            const float* sl = xs + (long long)s * DD;
            for (int li = tid; li < 240; li += 256)
                st_task41(raw, li, ld_task10(sl, ty0 - 4, tx0 - 4, li));
        }
        __syncthreads();
        if (inz && tid < 96) {
            // 16-read window serves 5-tap (X1) and 9-tap (X2) x-convs, 8 outputs each
            const float* rp = &raw[xr * 41 + 8 * xg];
            float win[16];
#pragma unroll
            for (int i = 0; i < 16; ++i) win[i] = rp[i];
            float4 p0 = make_float4(0.f, 0.f, 0.f, 0.f), p1 = p0;
            float4 q0 = make_float4(0.f, 0.f, 0.f, 0.f), q1 = q0;
#pragma unroll
            for (int k = 0; k < 5; ++k) {
                p0.x += czc[k] * win[2 + k];
                p0.y += czc[k] * win[3 + k];
                p0.z += czc[k] * win[4 + k];
                p0.w += czc[k] * win[5 + k];
                p1.x += czc[k] * win[6 + k];
                p1.y += czc[k] * win[7 + k];
                p1.z += czc[k] * win[8 + k];
                p1.w += czc[k] * win[9 + k];
            }
#pragma unroll
            for (int k = 0; k < 9; ++k) {
                q0.x += cxc[k] * win[k];
                q0.y += cxc[k] * win[1 + k];
                q0.z += cxc[k] * win[2 + k];
                q0.w += cxc[k] * win[3 + k];
                q1.x += cxc[k] * win[4 + k];
                q1.y += cxc[k] * win[5 + k];
                q1.z += cxc[k] * win[6 + k];
                q1.w += cxc[k] * win[7 + k];
            }
            *(float4*)&X1[xr][8 * xg] = p0;
            *(float4*)&X1[xr][8 * xg + 4] = p1;
            *(float4*)&X2[xr][8 * xg] = q0;
            *(float4*)&X2[xr][8 * xg + 4] = q1;
        }
        __syncthreads();
        float2 t1 = make_float2(0.f, 0.f), t2 = t1, t3 = t1;
        if (inz) {
#pragma unroll
            for (int k = 0; k < 5; ++k) {
                const float2 v = *(const float2*)&X1[rr + 2 + k][cc];
                t1.x += bz[k] * v.x; t1.y += bz[k] * v.y;
            }
#pragma unroll
            for (int k = 0; k < 9; ++k) {
                const float2 v = *(const float2*)&X1[rr + k][cc];
                t2.x += by[k] * v.x; t2.y += by[k] * v.y;
            }
#pragma unroll
            for (int k = 0; k < 5; ++k) {
                const float2 v = *(const float2*)&X2[rr + 2 + k][cc];
                t3.x += bx[k] * v.x; t3.y += bx[k] * v.y;
            }
        }
#pragma unroll
        for (int k = 0; k < 8; ++k) R1[k] = R1[k + 1];
        R1[8] = t1;
#pragma unroll
        for (int k = 0; k < 6; ++k) { R2[k] = R2[k + 1]; R3[k] = R3[k + 1]; }
        R2[6] = t2; R3[6] = t3;
        const int z = s - 4;
        if (z >= z0) {
            float gz0 = 0.f, gz1 = 0.f, gy0 = 0.f, gy1 = 0.f, gx0 = 0.f, gx1 = 0.f;
#pragma unroll
            for (int k = 0; k < 9; ++k) { gz0 += az[k] * R1[k].x; gz1 += az[k] * R1[k].y; }
#pragma unroll
            for (int k = 0; k < 5; ++k) {
                gy0 += ay[k] * R2[k].x; gy1 += ay[k] * R2[k].y;
                gx0 += ax[k] * R3[k].x; gx1 += ax[k] * R3[k].y;
            }
            float* o = G + (long long)z * DD + (ty0 + rr) * D + tx0 + cc;
            float2 wv;
            wv.x = gz0; wv.y = gz1; *(float2*)(o + 0 * V) = wv;
            wv.x = gy0; wv.y = gy1; *(float2*)(o + 1 * V) = wv;
            wv.x = gx0; wv.y = gx1; *(float2*)(o + 2 * V) = wv;
        }
    }
}

extern "C" void kernel_launch(void* const* d_in, const int* in_sizes, int n_in,
                              void* d_out, int out_size, void* d_ws, size_t ws_size,
                              hipStream_t stream) {
    const float* x  = (const float*)d_in[0];
    const float* g3 = (const float*)d_in[1];
    const float* kz = (const float*)d_in[2];
    const float* ky = (const float*)d_in[3];
    const float* kx = (const float*)d_in[4];
    float* out = (float*)d_out;

    float* coef = (float*)d_ws;
    float* G  = coef + 128;          // 3*V floats (gz, gy, gx)
    float* xs = G + 3 * V;           // V floats

    setup_coef<<<1, 64, 0, stream>>>(g3, kz, ky, kx, coef);

    // S1: Gaussian pre-smooth  x -> xs   (36 tiles x 32 segs = 1152 blocks)
    blur3d<6, 1, false><<<1152, 256, 0, stream>>>(x, xs, coef);

    // S2: gradients  xs -> G[3]         (72 tiles x 12 segs = 864 blocks, z-amp 1.5)
    grad3d<16><<<864, 256, 0, stream>>>(xs, G, coef);

    // S3: products-on-the-fly + grouped smoothing  G -> out
    //     (36 tiles x 6 ch x 6 segs = 1296 blocks, z-amp 1.19)
    blur3d<32, 6, true><<<1296, 256, 0, stream>>>(G, out, coef);
}

// Round 14
// 164.914 us; speedup vs baseline: 1.3070x; 1.3070x over previous
//
#include <hip/hip_runtime.h>

// 192^3 structure tensor, fused z-streaming pipeline (4 dispatches):
//   S0: setup_coef       (extract 1D rank-1 factors from the provided 3D kernels)
//   S1: blur3d_s1<12>    x -> xs    (32x16 tile, z-amp 1.5; S2-proven phase shapes)
//   S2: grad3d<16>       xs -> G[3] (gz,gy,gx; products deferred to S3)
//   S3: blur3d<32,6,true> G -> out  (products formed in regs at staging time)
// S2/S3 are byte-identical to the r12 best (165.3 us). r13 lesson: the conflict-free
// b128 LDS class is EXACTLY "1 row/thread, 8 rows x 8 quads/wave, stride-32"; the
// 8-output stride-41 xconv aliases at (dr=8,dg=3) and 2-row yconv aliases 8 lanes on
// one quad-column. No class extensions without measurement.

constexpr int D  = 192;
constexpr int DD = D * D;                  // 36864
constexpr long long V = (long long)D * DD; // 7077888

// coef layout (floats):
//  [0..6] ga  [7..13] gb  [14..20] gc   (gauss z,y,x)
//  [21..29] az (9)  [30..34] bz (5)  [35..39] cz (5)
//  [40..44] ay (5)  [45..53] by (9)  [54..58] cy (5, dup)
//  [59..63] ax (5)  [64..68] bx (5)  [69..77] cx (9)
__global__ void setup_coef(const float* __restrict__ g3, const float* __restrict__ kz,
                           const float* __restrict__ ky, const float* __restrict__ kx,
                           float* __restrict__ c) {
    if (blockIdx.x != 0 || threadIdx.x != 0) return;
    float Tg = g3[0];
    for (int i = 0; i < 7; ++i) c[0 + i]  = g3[i * 49];
    for (int j = 0; j < 7; ++j) c[7 + j]  = g3[j * 7] / Tg;
    for (int k = 0; k < 7; ++k) c[14 + k] = g3[k] / Tg;
    float Tz = kz[0];                      // kz: [9,5,5]
    for (int i = 0; i < 9; ++i) c[21 + i] = kz[i * 25];
    for (int j = 0; j < 5; ++j) c[30 + j] = kz[j * 5] / Tz;
    for (int k = 0; k < 5; ++k) c[35 + k] = kz[k] / Tz;
    float Ty = ky[0];                      // ky: [5,9,5]
    for (int i = 0; i < 5; ++i) c[40 + i] = ky[i * 45];
    for (int j = 0; j < 9; ++j) c[45 + j] = ky[j * 5] / Ty;
    for (int k = 0; k < 5; ++k) c[54 + k] = ky[k] / Ty;
    float Tx = kx[0];                      // kx: [5,5,9]
    for (int i = 0; i < 5; ++i) c[59 + i] = kx[i * 45];
    for (int j = 0; j < 5; ++j) c[64 + j] = kx[j * 9] / Tx;
    for (int k = 0; k < 9; ++k) c[69 + k] = kx[k] / Tx;
}

// Bounds-checked float4 load from one z-slice (row gy, cols gx..gx+3), zero-padded.
__device__ inline float4 ldg4(const float* __restrict__ slice, int gy, int gx) {
    float4 v = {0.f, 0.f, 0.f, 0.f};
    if ((unsigned)gy < (unsigned)D) {
        const float* row = slice + gy * D;
        if ((unsigned)gx <= (unsigned)(D - 4)) {
            v = *(const float4*)(row + gx);
        } else {
            float* pv = (float*)&v;
#pragma unroll
            for (int j = 0; j < 4; ++j) {
                const int g = gx + j;
                if ((unsigned)g < (unsigned)D) pv[j] = row[g];
            }
        }
    }
    return v;
}

// Dual-field bounds-hoisted load: computes bounds once, loads A and B rows.
__device__ inline void ldg4x2(const float* __restrict__ slA, const float* __restrict__ slB,
                              int gy, int gx, float4& a, float4& b) {
    a = make_float4(0.f, 0.f, 0.f, 0.f);
    b = a;
    if ((unsigned)gy < (unsigned)D) {
        const int ro = gy * D;
        if ((unsigned)gx <= (unsigned)(D - 4)) {
            a = *(const float4*)(slA + ro + gx);
            b = *(const float4*)(slB + ro + gx);
        } else {
            float* pa = (float*)&a;
            float* pb = (float*)&b;
#pragma unroll
            for (int j = 0; j < 4; ++j) {
                const int g = gx + j;
                if ((unsigned)g < (unsigned)D) { pa[j] = slA[ro + g]; pb[j] = slB[ro + g]; }
            }
        }
    }
}

// Staging task li -> (row li/10, quad li%10) of a (rows x 40) region, stride-41 LDS.
__device__ inline float4 ld_task10(const float* __restrict__ slice, int y0, int x0, int li) {
    const int r = li / 10, q = li % 10;
    return ldg4(slice, y0 + r, x0 + q * 4);
}
__device__ inline void st_task41(float* __restrict__ dst, int li, float4 v) {
    const int r = li / 10, q = li % 10;
    float* d = &dst[r * 41 + q * 4];
    d[0] = v.x; d[1] = v.y; d[2] = v.z; d[3] = v.w;   // b32 class: conflict-free
}

// ---- S1: fused separable 3D blur, 32x16 tile, float2 yconv, register z-ring ----
// 1D grid, XCD-swizzled; work = tile + 72*seg; grid = 72 * (192/SEG)
template <int SEG>
__global__ __launch_bounds__(256) void blur3d_s1(const float* __restrict__ in,
                                                 float* __restrict__ out,
                                                 const float* __restrict__ coef) {
    __shared__ float raw[22 * 41];
    __shared__ float xt[22][32];
    const int cpx = gridDim.x >> 3;
    int w = (blockIdx.x & 7) * cpx + (blockIdx.x >> 3);
    const int tile = w % 72;
    const int seg = w / 72;
    const int tx0 = (tile % 6) * 32, ty0 = (tile / 6) * 16;
    const int z0 = seg * SEG;
    float ga[7], gb[7], gc[7];
#pragma unroll
    for (int k = 0; k < 7; ++k) { ga[k] = coef[k]; gb[k] = coef[7 + k]; gc[k] = coef[14 + k]; }
    const int tid = threadIdx.x;
    const int rr = tid >> 4;                   // 0..15 (yconv rows)
    const int cc = (tid & 15) * 2;             // 0,2,..,30
    float2 ring[7];
#pragma unroll
    for (int k = 0; k < 7; ++k) ring[k] = make_float2(0.f, 0.f);

    for (int s = z0 - 3; s < z0 + SEG + 3; ++s) {
        const bool inz = (s >= 0 && s < D);
        if (inz && tid < 220) {
            const float* sl = in + (long long)s * DD;
            st_task41(raw, tid, ld_task10(sl, ty0 - 3, tx0 - 4, tid));
        }
        __syncthreads();                       // raw ready; prior xt readers done
        if (inz && tid < 176) {
            // r8-class 4-output sliding xconv: 10 scalar reads, 1 b128 write
            const int r = tid >> 3, g = tid & 7;
            const float* rp = &raw[r * 41 + 4 * g + 1];
            float win[10];
#pragma unroll
            for (int i = 0; i < 10; ++i) win[i] = rp[i];
            float4 o = make_float4(0.f, 0.f, 0.f, 0.f);
#pragma unroll
            for (int k = 0; k < 7; ++k) {
                o.x += gc[k] * win[k];
                o.y += gc[k] * win[k + 1];
                o.z += gc[k] * win[k + 2];
                o.w += gc[k] * win[k + 3];
            }
            *(float4*)&xt[r][4 * g] = o;
        }
        __syncthreads();                       // xt ready; raw readers done
        float2 yv = make_float2(0.f, 0.f);
        if (inz) {
#pragma unroll
            for (int k = 0; k < 7; ++k) {
                const float2 v = *(const float2*)&xt[rr + k][cc];
                yv.x += gb[k] * v.x; yv.y += gb[k] * v.y;
            }
        }
#pragma unroll
        for (int k = 0; k < 6; ++k) ring[k] = ring[k + 1];
        ring[6] = yv;
        const int z = s - 3;
        if (z >= z0) {
            float2 a = make_float2(0.f, 0.f);
#pragma unroll
            for (int k = 0; k < 7; ++k) {
                a.x += ga[k] * ring[k].x; a.y += ga[k] * ring[k].y;
            }
            *(float2*)(out + (long long)z * DD + (ty0 + rr) * D + tx0 + cc) = a;
        }
    }
}

// ---- S3: fused separable 3D blur, z-streaming, 32x32 tile (r12-proven) ----
// PROD=true: stage task loads two gradient fields and multiplies (product on the fly).
// 1D grid, XCD-swizzled; work = tile + 36*(ch + NCH*seg)
template <int SEG, int NCH, bool PROD>
__global__ __launch_bounds__(256) void blur3d(const float* __restrict__ in,
                                              float* __restrict__ out,
                                              const float* __restrict__ coef) {
    __shared__ float raw[38 * 41];
    __shared__ float xt[38][32];
    const int cpx = gridDim.x >> 3;
    int w = (blockIdx.x & 7) * cpx + (blockIdx.x >> 3);
    const int tile = w % 36; w /= 36;
    const int ch = w % NCH;
    const int seg = w / NCH;
    const int tx0 = (tile % 6) * 32, ty0 = (tile / 6) * 32;
    const int z0 = seg * SEG;
    // product channel -> gradient-field pair: [Jzz,Jzy,Jzx,Jyy,Jyx,Jxx]
    const int IA[6] = {0, 1, 2, 1, 2, 2};
    const int IB[6] = {0, 0, 0, 1, 1, 2};
    const float* srcA = in + (long long)(PROD ? IA[ch] : ch) * V;
    const float* srcB = in + (long long)(PROD ? IB[ch] : ch) * V;
    const bool same = !PROD || (IA[ch] == IB[ch]);
    float* dst = out + (long long)ch * V;
    float ga[7], gb[7], gc[7];
#pragma unroll
    for (int k = 0; k < 7; ++k) { ga[k] = coef[k]; gb[k] = coef[7 + k]; gc[k] = coef[14 + k]; }
    const int rr = threadIdx.x >> 3;          // 0..31
    const int cc = (threadIdx.x & 7) * 4;     // 0,4,..,28
    float4 ring[7];
#pragma unroll
    for (int k = 0; k < 7; ++k) ring[k] = make_float4(0.f, 0.f, 0.f, 0.f);

    for (int s = z0 - 3; s < z0 + SEG + 3; ++s) {
        const bool inz = (s >= 0 && s < D);
        if (inz) {
            const float* slA = srcA + (long long)s * DD;
            const float* slB = srcB + (long long)s * DD;
            if (same) {
                for (int li = threadIdx.x; li < 380; li += 256) {
                    float4 a = ld_task10(slA, ty0 - 3, tx0 - 4, li);
                    if (PROD) { a.x *= a.x; a.y *= a.y; a.z *= a.z; a.w *= a.w; }
                    st_task41(raw, li, a);
                }
            } else {
                for (int li = threadIdx.x; li < 380; li += 256) {
                    const int r = li / 10, q = li % 10;
                    float4 a, b;
                    ldg4x2(slA, slB, ty0 - 3 + r, tx0 - 4 + q * 4, a, b);
                    a.x *= b.x; a.y *= b.y; a.z *= b.z; a.w *= b.w;
                    float* d = &raw[r * 41 + q * 4];
                    d[0] = a.x; d[1] = a.y; d[2] = a.z; d[3] = a.w;
                }
            }
        }
        __syncthreads();                       // raw ready; prior xt readers done
        if (inz) {
            // 4-output sliding-window xconv: 10 scalar reads -> 4 outputs, b128 xt write
            for (int li = threadIdx.x; li < 38 * 8; li += 256) {
                const int r = li >> 3, g = li & 7;
                const float* rp = &raw[r * 41 + 4 * g + 1];
                float win[10];
#pragma unroll
                for (int i = 0; i < 10; ++i) win[i] = rp[i];
                float4 o = make_float4(0.f, 0.f, 0.f, 0.f);
#pragma unroll
                for (int k = 0; k < 7; ++k) {
                    o.x += gc[k] * win[k];
                    o.y += gc[k] * win[k + 1];
                    o.z += gc[k] * win[k + 2];
                    o.w += gc[k] * win[k + 3];
                }
                *(float4*)&xt[r][4 * g] = o;
            }
        }
        __syncthreads();                       // xt ready; raw readers done
        float4 yv = make_float4(0.f, 0.f, 0.f, 0.f);
        if (inz) {
#pragma unroll
            for (int k = 0; k < 7; ++k) {
                const float4 v = *(const float4*)&xt[rr + k][cc];
                yv.x += gb[k] * v.x; yv.y += gb[k] * v.y;
                yv.z += gb[k] * v.z; yv.w += gb[k] * v.w;
            }
        }
#pragma unroll
        for (int k = 0; k < 6; ++k) ring[k] = ring[k + 1];
        ring[6] = yv;
        const int z = s - 3;
        if (z >= z0) {
            float4 a = make_float4(0.f, 0.f, 0.f, 0.f);
#pragma unroll
            for (int k = 0; k < 7; ++k) {
                a.x += ga[k] * ring[k].x; a.y += ga[k] * ring[k].y;
                a.z += ga[k] * ring[k].z; a.w += ga[k] * ring[k].w;
            }
            *(float4*)(dst + (long long)z * DD + (ty0 + rr) * D + tx0 + cc) = a;
        }
    }
}

// ---- S2: fused gradients, z-streaming, 32x16 tile, register rings (r12-proven) ----
// 1D grid, XCD-swizzled; work = tile + 72*seg; writes gz,gy,gx to G[0..2]
template <int SEG>
__global__ __launch_bounds__(256) void grad3d(const float* __restrict__ xs,
                                              float* __restrict__ G,
                                              const float* __restrict__ coef) {
    __shared__ float raw[24 * 41];
    __shared__ float X1[24][32];
    __shared__ float X2[24][32];
    const int cpx = gridDim.x >> 3;
    int w = (blockIdx.x & 7) * cpx + (blockIdx.x >> 3);
    const int tile = w % 72;
    const int seg = w / 72;
    const int tx0 = (tile % 6) * 32, ty0 = (tile / 6) * 16;
    const int z0 = seg * SEG;
    float az[9], ay[5], ax[5], bz[5], by[9], bx[5], czc[5], cxc[9];
#pragma unroll
    for (int k = 0; k < 9; ++k) az[k] = coef[21 + k];
#pragma unroll
    for (int k = 0; k < 5; ++k) ay[k] = coef[40 + k];
#pragma unroll
    for (int k = 0; k < 5; ++k) ax[k] = coef[59 + k];
#pragma unroll
    for (int k = 0; k < 5; ++k) bz[k] = coef[30 + k];
#pragma unroll
    for (int k = 0; k < 9; ++k) by[k] = coef[45 + k];
#pragma unroll
    for (int k = 0; k < 5; ++k) bx[k] = coef[64 + k];
#pragma unroll
    for (int k = 0; k < 5; ++k) czc[k] = coef[35 + k];
#pragma unroll
    for (int k = 0; k < 9; ++k) cxc[k] = coef[69 + k];
    const int rr = threadIdx.x >> 4;           // 0..15
    const int cc = (threadIdx.x & 15) * 2;     // 0,2,..,30
    float2 R1[9], R2[7], R3[7];
#pragma unroll
    for (int k = 0; k < 9; ++k) R1[k] = make_float2(0.f, 0.f);
#pragma unroll
    for (int k = 0; k < 7; ++k) { R2[k] = make_float2(0.f, 0.f); R3[k] = make_float2(0.f, 0.f); }

    for (int s = z0 - 4; s < z0 + SEG + 4; ++s) {
        const bool inz = (s >= 0 && s < D);
        if (inz) {
            const float* sl = xs + (long long)s * DD;
            for (int li = threadIdx.x; li < 240; li += 256)
                st_task41(raw, li, ld_task10(sl, ty0 - 4, tx0 - 4, li));
        }
        __syncthreads();
        if (inz && threadIdx.x < 192) {
            const int r = threadIdx.x >> 3, g = threadIdx.x & 7;
            const float* rp = &raw[r * 41 + 4 * g];
            float win[12];
#pragma unroll
            for (int i = 0; i < 12; ++i) win[i] = rp[i];
            float4 o1 = make_float4(0.f, 0.f, 0.f, 0.f);
            float4 o2 = make_float4(0.f, 0.f, 0.f, 0.f);
#pragma unroll
            for (int k = 0; k < 5; ++k) {
                o1.x += czc[k] * win[2 + k];
                o1.y += czc[k] * win[3 + k];
                o1.z += czc[k] * win[4 + k];
                o1.w += czc[k] * win[5 + k];
            }
#pragma unroll
            for (int k = 0; k < 9; ++k) {
                o2.x += cxc[k] * win[k];
                o2.y += cxc[k] * win[1 + k];
                o2.z += cxc[k] * win[2 + k];
                o2.w += cxc[k] * win[3 + k];
            }
            *(float4*)&X1[r][4 * g] = o1;
            *(float4*)&X2[r][4 * g] = o2;
        }
        __syncthreads();
        float2 t1 = make_float2(0.f, 0.f), t2 = t1, t3 = t1;
        if (inz) {
#pragma unroll
            for (int k = 0; k < 5; ++k) {
                const float2 v = *(const float2*)&X1[rr + 2 + k][cc];
                t1.x += bz[k] * v.x; t1.y += bz[k] * v.y;
            }
#pragma unroll
            for (int k = 0; k < 9; ++k) {
                const float2 v = *(const float2*)&X1[rr + k][cc];
                t2.x += by[k] * v.x; t2.y += by[k] * v.y;
            }
#pragma unroll
            for (int k = 0; k < 5; ++k) {
                const float2 v = *(const float2*)&X2[rr + 2 + k][cc];
                t3.x += bx[k] * v.x; t3.y += bx[k] * v.y;
            }
        }
#pragma unroll
        for (int k = 0; k < 8; ++k) R1[k] = R1[k + 1];
        R1[8] = t1;
#pragma unroll
        for (int k = 0; k < 6; ++k) { R2[k] = R2[k + 1]; R3[k] = R3[k + 1]; }
        R2[6] = t2; R3[6] = t3;
        const int z = s - 4;
        if (z >= z0) {
            float gz0 = 0.f, gz1 = 0.f, gy0 = 0.f, gy1 = 0.f, gx0 = 0.f, gx1 = 0.f;
#pragma unroll
            for (int k = 0; k < 9; ++k) { gz0 += az[k] * R1[k].x; gz1 += az[k] * R1[k].y; }
#pragma unroll
            for (int k = 0; k < 5; ++k) {
                gy0 += ay[k] * R2[k].x; gy1 += ay[k] * R2[k].y;
                gx0 += ax[k] * R3[k].x; gx1 += ax[k] * R3[k].y;
            }
            float* o = G + (long long)z * DD + (ty0 + rr) * D + tx0 + cc;
            float2 wv;
            wv.x = gz0; wv.y = gz1; *(float2*)(o + 0 * V) = wv;
            wv.x = gy0; wv.y = gy1; *(float2*)(o + 1 * V) = wv;
            wv.x = gx0; wv.y = gx1; *(float2*)(o + 2 * V) = wv;
        }
    }
}

extern "C" void kernel_launch(void* const* d_in, const int* in_sizes, int n_in,
                              void* d_out, int out_size, void* d_ws, size_t ws_size,
                              hipStream_t stream) {
    const float* x  = (const float*)d_in[0];
    const float* g3 = (const float*)d_in[1];
    const float* kz = (const float*)d_in[2];
    const float* ky = (const float*)d_in[3];
    const float* kx = (const float*)d_in[4];
    float* out = (float*)d_out;

    float* coef = (float*)d_ws;
    float* G  = coef + 128;          // 3*V floats (gz, gy, gx)
    float* xs = G + 3 * V;           // V floats

    setup_coef<<<1, 64, 0, stream>>>(g3, kz, ky, kx, coef);

    // S1: Gaussian pre-smooth  x -> xs   (72 tiles x 16 segs = 1152 blocks, z-amp 1.5)
    blur3d_s1<12><<<1152, 256, 0, stream>>>(x, xs, coef);

    // S2: gradients  xs -> G[3]         (72 tiles x 12 segs = 864 blocks, z-amp 1.5)
    grad3d<16><<<864, 256, 0, stream>>>(xs, G, coef);

    // S3: products-on-the-fly + grouped smoothing  G -> out
    //     (36 tiles x 6 ch x 6 segs = 1296 blocks, z-amp 1.19)
    blur3d<32, 6, true><<<1296, 256, 0, stream>>>(G, out, coef);
}